// Round 1
// baseline (149.346 us; speedup 1.0000x reference)
//
#include <hip/hip_runtime.h>

// WaveletLayer on [4096,4096] fp32:
//   out = diag_s * DWT3( diag_g * (DWT3(diag_b * x))[perm] )
// Haar DWT3 packet layout: [cA3(512) | cD3(512) | cD2(1024) | cD1(2048)].
//
// Block of 256 threads processes R=4 rows. DWTs run fully in registers
// (thread owns 16 contiguous columns); LDS only for the permutation
// round-trip, double-buffered, 1 barrier/row.
//
// v2 (this round): the kernel was latency-bound (VALUBusy 7.6%, HBM 33%).
// __syncthreads() emits s_waitcnt vmcnt(0) before s_barrier, which (a)
// drained the row's global loads at every barrier (no cross-row load
// pipelining) and (b) serialized the previous row's nontemporal-store
// acknowledgments into each row iteration. The barrier only needs to order
// LDS scatter vs gather, so:
//   1. replace __syncthreads with an LDS-only barrier
//      (s_waitcnt lgkmcnt(0) + raw s_barrier, sched_barrier-fenced), and
//   2. software-pipeline: issue row r+1's loads before row r's barrier;
//      they stay in flight across it.

#define D   4096
#define NT  256            // 16 columns / thread
#define R   4              // rows per block

#define C_INV_SQRT2 0.70710678118654752440f

typedef float vf2 __attribute__((ext_vector_type(2)));
typedef float vf4 __attribute__((ext_vector_type(4)));

// XOR swizzle to break power-of-2 patterns on the scatter writes.
static __device__ __forceinline__ int swz(int i) {
    return i ^ ((i >> 5) & 31);
}

// LDS-only barrier: order ds_write (scatter) vs ds_read (gather) across the
// block WITHOUT draining vmcnt — outstanding global loads (next-row
// prefetch) and nontemporal stores stay in flight.
// sched_barrier(0) + "memory" clobber pin the ds ops on the correct side
// (rule: compiler may move mem ops across a bare s_barrier builtin).
static __device__ __forceinline__ void lds_barrier() {
    __builtin_amdgcn_sched_barrier(0);
    asm volatile("s_waitcnt lgkmcnt(0)" ::: "memory");
    __builtin_amdgcn_s_barrier();
    __builtin_amdgcn_sched_barrier(0);
}

// 3 in-register Haar levels on 16 contiguous elements.
static __device__ __forceinline__ void dwt3_reg(const float v[16],
                                                float a3[2], float d3[2],
                                                float d2[4], float d1[8]) {
    float a1[8];
    #pragma unroll
    for (int j = 0; j < 8; ++j) {
        a1[j] = (v[2 * j] + v[2 * j + 1]) * C_INV_SQRT2;
        d1[j] = (v[2 * j] - v[2 * j + 1]) * C_INV_SQRT2;
    }
    float a2[4];
    #pragma unroll
    for (int j = 0; j < 4; ++j) {
        a2[j] = (a1[2 * j] + a1[2 * j + 1]) * C_INV_SQRT2;
        d2[j] = (a1[2 * j] - a1[2 * j + 1]) * C_INV_SQRT2;
    }
    #pragma unroll
    for (int j = 0; j < 2; ++j) {
        a3[j] = (a2[2 * j] + a2[2 * j + 1]) * C_INV_SQRT2;
        d3[j] = (a2[2 * j] - a2[2 * j + 1]) * C_INV_SQRT2;
    }
}

__global__ __launch_bounds__(NT, 4) void wavelet_rows_kernel(
    const float* __restrict__ x,
    const float* __restrict__ diag_s,
    const float* __restrict__ diag_g,
    const float* __restrict__ diag_b,
    const int*   __restrict__ perm,
    float*       __restrict__ out)
{
    __shared__ float buf[2][D];

    const int t = threadIdx.x;
    const size_t row0 = (size_t)blockIdx.x * R;

    // ---- load row-invariant tables into registers (once per block) ----
    float db[16], dg[16];
    int   pidx[16];
    {
        const vf4* b4 = (const vf4*)diag_b;
        const vf4* g4 = (const vf4*)diag_g;
        const int4* p4 = (const int4*)perm;
        #pragma unroll
        for (int k = 0; k < 4; ++k) {
            vf4 bv = b4[4 * t + k];
            db[4 * k + 0] = bv.x; db[4 * k + 1] = bv.y;
            db[4 * k + 2] = bv.z; db[4 * k + 3] = bv.w;
            vf4 gv = g4[4 * t + k];
            dg[4 * k + 0] = gv.x; dg[4 * k + 1] = gv.y;
            dg[4 * k + 2] = gv.z; dg[4 * k + 3] = gv.w;
            int4 pv = p4[4 * t + k];
            pidx[4 * k + 0] = pv.x; pidx[4 * k + 1] = pv.y;
            pidx[4 * k + 2] = pv.z; pidx[4 * k + 3] = pv.w;
        }
    }
    // diag_s at the thread-fixed packet store positions:
    vf2 sA, sD3;
    vf4 sD2, sD1a, sD1b;
    {
        const vf2* s2 = (const vf2*)diag_s;
        const vf4* s4 = (const vf4*)diag_s;
        sA   = s2[t];               // floats 2t, 2t+1      (cA3)
        sD3  = s2[256 + t];         // floats 512+2t..      (cD3)
        sD2  = s4[256 + t];         // floats 1024+4t..     (cD2)
        sD1a = s4[512 + 2 * t];     // floats 2048+8t..     (cD1)
        sD1b = s4[512 + 2 * t + 1];
    }

    // ---- prologue: issue row 0's loads ----
    vf4 xv[4];
    {
        const vf4* x4 = (const vf4*)(x + row0 * (size_t)D);
        #pragma unroll
        for (int k = 0; k < 4; ++k) xv[k] = x4[4 * t + k];
    }

    // ---- row loop (fully unrolled; 1 LDS-only barrier per row) ----
    #pragma unroll
    for (int r = 0; r < R; ++r) {
        float* b = buf[r & 1];

        // consume current row's loads, multiply diag_b
        float v[16];
        #pragma unroll
        for (int k = 0; k < 4; ++k) {
            v[4 * k + 0] = xv[k].x * db[4 * k + 0];
            v[4 * k + 1] = xv[k].y * db[4 * k + 1];
            v[4 * k + 2] = xv[k].z * db[4 * k + 2];
            v[4 * k + 3] = xv[k].w * db[4 * k + 3];
        }

        // prefetch next row NOW — these loads remain in flight across the
        // LDS-only barrier below (no vmcnt drain) and complete under row
        // r's gather/DWT2/store work.
        if (r + 1 < R) {
            const vf4* xn = (const vf4*)(x + (row0 + r + 1) * (size_t)D);
            #pragma unroll
            for (int k = 0; k < 4; ++k) xv[k] = xn[4 * t + k];
        }

        // DWT #1 in registers
        float a3[2], d3[2], d2[4], d1[8];
        dwt3_reg(v, a3, d3, d2, d1);

        // scatter packet layout to LDS (swizzled)
        #pragma unroll
        for (int j = 0; j < 2; ++j) b[swz(2 * t + j)]        = a3[j];
        #pragma unroll
        for (int j = 0; j < 2; ++j) b[swz(512 + 2 * t + j)]  = d3[j];
        #pragma unroll
        for (int j = 0; j < 4; ++j) b[swz(1024 + 4 * t + j)] = d2[j];
        #pragma unroll
        for (int j = 0; j < 8; ++j) b[swz(2048 + 8 * t + j)] = d1[j];

        // LDS-only barrier (no vmcnt drain)
        lds_barrier();

        // permutation gather * diag_g
        float w[16];
        #pragma unroll
        for (int k = 0; k < 16; ++k) {
            w[k] = b[swz(pidx[k])] * dg[k];
        }

        // DWT #2 in registers
        float b3[2], e3[2], e2[4], e1[8];
        dwt3_reg(w, b3, e3, e2, e1);

        // multiply diag_s, nontemporal coalesced store
        float* orow = out + (row0 + r) * (size_t)D;
        {
            vf2* o2 = (vf2*)orow;
            vf2 ov;
            ov.x = b3[0] * sA.x;  ov.y = b3[1] * sA.y;
            __builtin_nontemporal_store(ov, &o2[t]);
            ov.x = e3[0] * sD3.x; ov.y = e3[1] * sD3.y;
            __builtin_nontemporal_store(ov, &o2[256 + t]);

            vf4* o4 = (vf4*)orow;
            vf4 o;
            o.x = e2[0] * sD2.x; o.y = e2[1] * sD2.y;
            o.z = e2[2] * sD2.z; o.w = e2[3] * sD2.w;
            __builtin_nontemporal_store(o, &o4[256 + t]);
            o.x = e1[0] * sD1a.x; o.y = e1[1] * sD1a.y;
            o.z = e1[2] * sD1a.z; o.w = e1[3] * sD1a.w;
            __builtin_nontemporal_store(o, &o4[512 + 2 * t]);
            o.x = e1[4] * sD1b.x; o.y = e1[5] * sD1b.y;
            o.z = e1[6] * sD1b.z; o.w = e1[7] * sD1b.w;
            __builtin_nontemporal_store(o, &o4[512 + 2 * t + 1]);
        }
        // Buffer-reuse safety (unchanged from v1): scatter into buf[(r+2)&1]
        // happens after the barrier of row r+1, which follows this row's
        // gather in program order on every wave.
    }
}

extern "C" void kernel_launch(void* const* d_in, const int* in_sizes, int n_in,
                              void* d_out, int out_size, void* d_ws, size_t ws_size,
                              hipStream_t stream) {
    // setup_inputs() order: x, diag_s, diag_g, diag_b, dec_lo, dec_hi, perm, scales
    const float* x      = (const float*)d_in[0];
    const float* diag_s = (const float*)d_in[1];
    const float* diag_g = (const float*)d_in[2];
    const float* diag_b = (const float*)d_in[3];
    const int* perm     = (const int*)d_in[6];
    float* out          = (float*)d_out;

    const int B = 4096 / R;
    wavelet_rows_kernel<<<B, NT, 0, stream>>>(x, diag_s, diag_g, diag_b, perm, out);
}